// Round 1
// baseline (500.788 us; speedup 1.0000x reference)
//
#include <hip/hip_runtime.h>
#include <hip/hip_bf16.h>

#define IN_DIM  5120
#define OUT_DIM 1858

// ---------------------------------------------------------------------------
// Pass 1: scan fc1 [IN_DIM, OUT_DIM] (row-major) and build the gather map:
//   idx[j] = i such that fc1[i][j] != 0,  val[j] = fc1[i][j]
// Exactly one nonzero per column by construction, so plain stores are safe.
// idx[] is pre-initialized to -1 (memsetAsync 0xFF) so all-zero columns
// (if any) produce output 0.
// ---------------------------------------------------------------------------
__global__ void build_map_kernel(const float* __restrict__ fc1,
                                 int* __restrict__ idx,
                                 float* __restrict__ val) {
    const int total4 = (IN_DIM * OUT_DIM) / 4;   // 9,512,960 / 4
    int t = blockIdx.x * blockDim.x + threadIdx.x;
    if (t >= total4) return;
    float4 v = reinterpret_cast<const float4*>(fc1)[t];
    int base = t * 4;
#pragma unroll
    for (int k = 0; k < 4; ++k) {
        float f = (&v.x)[k];
        if (f != 0.0f) {
            int e = base + k;
            int i = e / OUT_DIM;          // compiler: magic-mul
            int j = e - i * OUT_DIM;
            idx[j] = i;
            val[j] = f;
        }
    }
}

// ---------------------------------------------------------------------------
// Pass 2: one block per batch row. Stage the 5120-float row in LDS with
// coalesced float4 loads, then gather: out[b][j] = row[idx[j]] * val[j].
// Writes are fully coalesced (64 contiguous floats per wave).
// LDS = 20 KB/block -> 8 blocks/CU, 32 waves/CU (full occupancy).
// ---------------------------------------------------------------------------
__global__ __launch_bounds__(256)
void gather_policy_kernel(const float* __restrict__ x,
                          const int* __restrict__ idx,
                          const float* __restrict__ val,
                          float* __restrict__ out) {
    __shared__ float row[IN_DIM];

    const int b = blockIdx.x;
    const float* xr = x + (size_t)b * IN_DIM;

    // coalesced row load: 1280 float4s, 256 threads -> 5 iterations
#pragma unroll
    for (int t = threadIdx.x; t < IN_DIM / 4; t += 256) {
        reinterpret_cast<float4*>(row)[t] =
            reinterpret_cast<const float4*>(xr)[t];
    }
    __syncthreads();

    float* outr = out + (size_t)b * OUT_DIM;
    for (int j = threadIdx.x; j < OUT_DIM; j += 256) {
        int i = idx[j];
        outr[j] = (i >= 0) ? row[i] * val[j] : 0.0f;
    }
}

extern "C" void kernel_launch(void* const* d_in, const int* in_sizes, int n_in,
                              void* d_out, int out_size, void* d_ws, size_t ws_size,
                              hipStream_t stream) {
    const float* x   = (const float*)d_in[0];
    const float* fc1 = (const float*)d_in[1];
    float* out = (float*)d_out;

    const int B = in_sizes[0] / IN_DIM;   // 16384

    // workspace layout: idx[OUT_DIM] ints, then val[OUT_DIM] floats
    int*   idx = (int*)d_ws;
    float* val = (float*)((char*)d_ws + OUT_DIM * sizeof(int));

    // idx = -1 everywhere (0xFF bytes). d_ws is re-poisoned before every
    // timed call, so this must run every launch.
    hipMemsetAsync(idx, 0xFF, OUT_DIM * sizeof(int), stream);

    const int total4 = (IN_DIM * OUT_DIM) / 4;
    build_map_kernel<<<(total4 + 255) / 256, 256, 0, stream>>>(fc1, idx, val);

    gather_policy_kernel<<<B, 256, 0, stream>>>(x, idx, val, out);
}

// Round 3
// 495.761 us; speedup vs baseline: 1.0101x; 1.0101x over previous
//
#include <hip/hip_runtime.h>
#include <hip/hip_bf16.h>

#define IN_DIM  5120
#define OUT_DIM 1858
#define ROWS_PER_BLK 2

// ---------------------------------------------------------------------------
// Pass 1: scan fc1 [IN_DIM, OUT_DIM] (row-major) and build the gather map:
//   idx[j] = i such that fc1[i][j] != 0,  val[j] = fc1[i][j]
// Exactly one nonzero per column by construction -> every idx[j]/val[j] is
// written exactly once; no init needed. (d_ws poison 0xAA = negative int, and
// the gather kernel guards i >= 0, so even a hypothetical all-zero column is
// safe without a memset.)
// ---------------------------------------------------------------------------
__global__ __launch_bounds__(256)
void build_map_kernel(const float* __restrict__ fc1,
                      int* __restrict__ idx,
                      float* __restrict__ val) {
    const int total4 = (IN_DIM * OUT_DIM) / 4;   // 2,378,240
    int t = blockIdx.x * blockDim.x + threadIdx.x;
    if (t >= total4) return;
    float4 v = reinterpret_cast<const float4*>(fc1)[t];
    int base = t * 4;
#pragma unroll
    for (int k = 0; k < 4; ++k) {
        float f = (&v.x)[k];
        if (f != 0.0f) {
            int e = base + k;
            int i = e / OUT_DIM;          // compile-time const divisor: magic-mul
            int j = e - i * OUT_DIM;
            idx[j] = i;
            val[j] = f;
        }
    }
}

// ---------------------------------------------------------------------------
// Pass 2: ROWS_PER_BLK batch rows per 256-thread block. Stage the rows in LDS
// with coalesced float4 loads (40 KB -> 4 blocks/CU, 16 waves/CU), then
// gather with paired int2/float2 accesses:
//   out[b][2j..2j+1] = row[idx[2j..2j+1]] * val[2j..2j+1]
// idx/val are read once per j-pair and reused across the ROWS_PER_BLK rows.
// All global loads/stores fully coalesced; OUT_DIM=1858 is even and row byte
// stride 7432 is 8-aligned, so float2 stores are legal with no tail.
// ---------------------------------------------------------------------------
__global__ __launch_bounds__(256)
void gather_policy_kernel(const float* __restrict__ x,
                          const int* __restrict__ idx,
                          const float* __restrict__ val,
                          float* __restrict__ out) {
    __shared__ float rows[ROWS_PER_BLK][IN_DIM];

    const int b0 = blockIdx.x * ROWS_PER_BLK;
    const float* xr = x + (size_t)b0 * IN_DIM;

    // coalesced stage: ROWS_PER_BLK*1280 float4s, 256 threads
#pragma unroll
    for (int t = threadIdx.x; t < ROWS_PER_BLK * IN_DIM / 4; t += 256) {
        reinterpret_cast<float4*>(&rows[0][0])[t] =
            reinterpret_cast<const float4*>(xr)[t];
    }
    __syncthreads();

    const int2*   idx2 = reinterpret_cast<const int2*>(idx);
    const float2* val2 = reinterpret_cast<const float2*>(val);

    for (int j = threadIdx.x; j < OUT_DIM / 2; j += 256) {
        int2   ii = idx2[j];
        float2 vv = val2[j];
#pragma unroll
        for (int r = 0; r < ROWS_PER_BLK; ++r) {
            float2 o;
            o.x = (ii.x >= 0) ? rows[r][ii.x] * vv.x : 0.0f;
            o.y = (ii.y >= 0) ? rows[r][ii.y] * vv.y : 0.0f;
            reinterpret_cast<float2*>(out + (size_t)(b0 + r) * OUT_DIM)[j] = o;
        }
    }
}

extern "C" void kernel_launch(void* const* d_in, const int* in_sizes, int n_in,
                              void* d_out, int out_size, void* d_ws, size_t ws_size,
                              hipStream_t stream) {
    const float* x   = (const float*)d_in[0];
    const float* fc1 = (const float*)d_in[1];
    float* out = (float*)d_out;

    const int B = in_sizes[0] / IN_DIM;   // 16384

    // workspace: idx[OUT_DIM] ints, then val[OUT_DIM] floats (offset 7432 is
    // 8-byte aligned for the int2/float2 views)
    int*   idx = (int*)d_ws;
    float* val = (float*)((char*)d_ws + OUT_DIM * sizeof(int));

    const int total4 = (IN_DIM * OUT_DIM) / 4;
    build_map_kernel<<<(total4 + 255) / 256, 256, 0, stream>>>(fc1, idx, val);

    gather_policy_kernel<<<B / ROWS_PER_BLK, 256, 0, stream>>>(x, idx, val, out);
}